// Round 13
// baseline (62.623 us; speedup 1.0000x reference)
//
#include <hip/hip_runtime.h>

#define NB 64
#define NE 40000
#define DIM 200
#define NL 100
#define EBLK 32
#define NTHREADS 256
#define D4 50          // float4 per E row
#define L4 25          // float4 per num_lit row
#define LOG2E 1.4426950408889634f

#define WS_E1R 0       // bf16 [64][224] (e1*r):             28672 B
#define WS_ASW 28672   // f32 [100][64][2] ({as,w} per b):    51200 B
                       // total ws use: 79872 B  (SESSION RULE: <= 79872)

// LDS arena (phase-disjoint lifetimes):
//   phase 1 : A [0,16384) + Bm [16384,24576)
//   scatter : scat [0,8448)
//   phase 2 : xsF [0,12800)
#define A_OFF    0
#define BM_OFF   16384
#define SCAT_OFF 0
#define XS_OFF   0
#define SMEM_BYTES 24576

typedef float f32x4 __attribute__((ext_vector_type(4)));
typedef short bf16x8 __attribute__((ext_vector_type(8)));
// SESSION RULE (r4/r5/r7/r8/r9): NO f32x2 packed arithmetic — every build
// using it failed with build-varying absmax 0.027-0.063. Scalar math only.

__device__ __forceinline__ unsigned int f2bf(float f) {
    unsigned int u = __float_as_uint(f);
    return (u + 0x7fffu + ((u >> 16) & 1u)) >> 16;  // RNE
}
__device__ __forceinline__ unsigned int packbf(float a, float b) {
    return f2bf(a) | (f2bf(b) << 16);
}

// ---------------- pre-kernel: bake e1*r (bf16) and asw (f32) into d_ws ----------------
__global__ void DistMult_prep_kernel(
    const int* __restrict__ e1_idx, const int* __restrict__ r_idx,
    const float* __restrict__ Ew, const float* __restrict__ Rw,
    const float* __restrict__ num_lit, const float* __restrict__ cvec,
    const float* __restrict__ var, const float* __restrict__ nfw,
    unsigned char* __restrict__ ws)
{
    const int t = blockIdx.x * NTHREADS + threadIdx.x;  // grid 8*256 = 2048
    unsigned int* e1r = (unsigned int*)(ws + WS_E1R);   // 112 uint per row
    const float4* E4 = (const float4*)Ew;
    const float4* R4 = (const float4*)Rw;

    // e1r bf16 [64][224]
    for (int f = t; f < NB * 28; f += 8 * NTHREADS) {
        int b = f / 28, c = f % 28;
        uint4 st = {0u, 0u, 0u, 0u};
        if (c < 25) {
            float4 a0 = E4[(size_t)e1_idx[b] * D4 + 2 * c];
            float4 a1 = E4[(size_t)e1_idx[b] * D4 + 2 * c + 1];
            float4 r0 = R4[(size_t)r_idx[b] * D4 + 2 * c];
            float4 r1 = R4[(size_t)r_idx[b] * D4 + 2 * c + 1];
            st.x = packbf(a0.x * r0.x, a0.y * r0.y);
            st.y = packbf(a0.z * r0.z, a0.w * r0.w);
            st.z = packbf(a1.x * r1.x, a1.y * r1.y);
            st.w = packbf(a1.z * r1.z, a1.w * r1.w);
        }
        *(uint4*)(e1r + (size_t)b * 112 + c * 4) = st;
    }

    // asw f32 [100][64][2]: as = (n_h - c)*s, w = nfw gather.
    float2* asw = (float2*)(ws + WS_ASW);
    for (int f = t; f < NL * NB; f += 8 * NTHREADS) {
        int b = f & 63, l = f >> 6;
        float s = sqrtf(LOG2E / var[l]);
        float2 v;
        v.x = (num_lit[(size_t)e1_idx[b] * NL + l] - cvec[l]) * s;
        v.y = nfw[(size_t)r_idx[b] * NL + l];
        asw[f] = v;   // f == l*64 + b
    }
}

// ---------------- main kernel ----------------
// Phase 1: MFMA + layout probe + scatter (r6-verified bridge).
// Phase 2: single 100-l loop, software-pipelined depth-2 (prefetch asw from
// L2 and xs from LDS one iteration ahead to hide the 120-300 cyc latencies).
__global__ __launch_bounds__(NTHREADS, 5)
void DistMult_KBLN_79164837200204_kernel(
    const float* __restrict__ Ew, const float* __restrict__ num_lit,
    const float* __restrict__ var,
    const unsigned char* __restrict__ ws, float* __restrict__ out)
{
    __shared__ __align__(16) char smem[SMEM_BYTES];
    __shared__ float sS[NL];

    const int t = threadIdx.x;
    // Bijective XCD-chunked swizzle (m204), nwg = 1250.
    const int nq = (NE / EBLK) >> 3, nr = (NE / EBLK) & 7;
    const int xcd = blockIdx.x & 7, sub = blockIdx.x >> 3;
    const int wg = (xcd < nr ? xcd * (nq + 1) : nr * (nq + 1) + (xcd - nr) * nq) + sub;
    const int e0 = wg * EBLK;

    const int L = t & 63, w = t >> 6;
    const int l15 = L & 15, lq = L >> 4;
    const int tx = t & 7, ty = t >> 3;

    if (t < NL) sS[t] = sqrtf(LOG2E / var[t]);

    // ======== layout probe (r6-verified): true (b,e) of each acc slot ========
    unsigned short* pA  = (unsigned short*)(smem + A_OFF);   // row stride 32
    unsigned short* pBm = (unsigned short*)(smem + BM_OFF);
    for (int i = t; i < 1024; i += NTHREADS) ((unsigned int*)pA)[i] = 0u;
    for (int i = t; i < 512;  i += NTHREADS) ((unsigned int*)pBm)[i] = 0u;
    __syncthreads();
    if (t < 64) {
        pA[t * 32]     = (unsigned short)f2bf(256.0f * t);
        pA[t * 32 + 1] = (unsigned short)f2bf(1.0f);
    } else if (t < 96) {
        int e = t - 64;
        pBm[e * 32]     = (unsigned short)f2bf(1.0f);
        pBm[e * 32 + 1] = (unsigned short)f2bf((float)e);
    }
    __syncthreads();
    int ib0[4], ib1[4];
    {
        bf16x8 afp = *(const bf16x8*)(pA + (16 * w + l15) * 32 + lq * 8);
        bf16x8 b0p = *(const bf16x8*)(pBm + l15 * 32 + lq * 8);
        bf16x8 b1p = *(const bf16x8*)(pBm + (16 + l15) * 32 + lq * 8);
        f32x4 z = {0.f, 0.f, 0.f, 0.f};
        f32x4 p0 = __builtin_amdgcn_mfma_f32_16x16x32_bf16(afp, b0p, z, 0, 0, 0);
        f32x4 p1 = __builtin_amdgcn_mfma_f32_16x16x32_bf16(afp, b1p, z, 0, 0, 0);
        #pragma unroll
        for (int r = 0; r < 4; ++r) { ib0[r] = (int)p0[r]; ib1[r] = (int)p1[r]; }
    }
    __syncthreads();

    f32x4 acc0 = {0.f, 0.f, 0.f, 0.f};
    f32x4 acc1 = {0.f, 0.f, 0.f, 0.f};

    const float4* E4 = (const float4*)Ew;
    const uint4* wsA = (const uint4*)(ws + WS_E1R);  // 28 uint4 per row

    // ============ phase 1: score_l via MFMA, 2 K-halves (128 / 96) ============
    #pragma unroll
    for (int h = 0; h < 2; ++h) {
        const int nc = h ? 12 : 16;
        for (int f = t; f < NB * nc; f += NTHREADS) {
            int b = f / nc, c = f % nc;
            uint4 v = wsA[(size_t)b * 28 + h * 16 + c];
            int off = (b * 256 + c * 16) ^ ((b & 7) << 4);
            *(uint4*)(smem + A_OFF + off) = v;
        }
        for (int f = t; f < EBLK * nc; f += NTHREADS) {
            int e = f / nc, c = f % nc;
            int dg = h * 128 + c * 8;
            uint4 st = {0u, 0u, 0u, 0u};
            if (dg <= DIM - 8) {
                float4 v0 = E4[(size_t)(e0 + e) * D4 + (dg >> 2)];
                float4 v1 = E4[(size_t)(e0 + e) * D4 + (dg >> 2) + 1];
                st.x = packbf(v0.x, v0.y);
                st.y = packbf(v0.z, v0.w);
                st.z = packbf(v1.x, v1.y);
                st.w = packbf(v1.z, v1.w);
            }
            int off = (e * 256 + c * 16) ^ ((e & 7) << 4);
            *(uint4*)(smem + BM_OFF + off) = st;
        }
        __syncthreads();

        const int nst = h ? 3 : 4;
        const int arow = 16 * w + l15;
        const int aswz = (arow & 7) << 4;
        const int bswz = (l15 & 7) << 4;
        #pragma unroll
        for (int s = 0; s < 4; ++s) {
            if (s < nst) {
                int kb = s * 64 + lq * 16;
                bf16x8 af = *(const bf16x8*)(smem + A_OFF + ((arow * 256 + kb) ^ aswz));
                bf16x8 b0 = *(const bf16x8*)(smem + BM_OFF + ((l15 * 256 + kb) ^ bswz));
                bf16x8 b1 = *(const bf16x8*)(smem + BM_OFF + (((16 + l15) * 256 + kb) ^ bswz));
                acc0 = __builtin_amdgcn_mfma_f32_16x16x32_bf16(af, b0, acc0, 0, 0, 0);
                acc1 = __builtin_amdgcn_mfma_f32_16x16x32_bf16(af, b1, acc1, 0, 0, 0);
            }
        }
        __syncthreads();
    }

    // ======== scatter acc via probed coords, gather at r3 map ========
    float* scat = (float*)(smem + SCAT_OFF);
    #pragma unroll
    for (int r = 0; r < 4; ++r) {
        scat[(ib0[r] >> 8) * 33 + (ib0[r] & 255)] = acc0[r];
        scat[(ib1[r] >> 8) * 33 + (ib1[r] & 255)] = acc1[r];
    }
    __syncthreads();

    float2 acc2[4];
    #pragma unroll
    for (int j = 0; j < 4; ++j) {
        acc2[j].x = scat[(2 * ty) * 33 + 4 * tx + j];
        acc2[j].y = scat[(2 * ty + 1) * 33 + 4 * tx + j];
    }
    __syncthreads();

    // ======== stage xsF[100][32] once (conflict-free e-major writes) ========
    const float4* N4 = (const float4*)num_lit;
    float* xsF = (float*)(smem + XS_OFF);
    for (int f = t; f < EBLK * L4; f += NTHREADS) {
        int e = f & 31, l4 = f >> 5;
        float4 v = N4[(size_t)(e0 + e) * L4 + l4];
        const float* vf = (const float*)&v;
        #pragma unroll
        for (int k = 0; k < 4; ++k)
            xsF[(4 * l4 + k) * 32 + e] = vf[k] * sS[4 * l4 + k];
    }
    __syncthreads();   // the ONLY phase-2 barrier

    // ============ phase 2: software-pipelined depth-2 (prefetch l+1) ============
    const float4* ASW = (const float4*)(ws + WS_ASW);  // [100][32] float4
    float4 aw = ASW[ty];                               // l = 0
    float4 xs = *(const float4*)(xsF + 4 * tx);
    #pragma unroll 2
    for (int l = 0; l < NL; ++l) {
        float4 aw_n, xs_n;
        if (l < NL - 1) {
            aw_n = ASW[(l + 1) * 32 + ty];             // prefetch: L2 latency
            xs_n = *(const float4*)(xsF + (l + 1) * 32 + 4 * tx);  // LDS latency
        }
        float xj[4] = { xs.x, xs.y, xs.z, xs.w };
        #pragma unroll
        for (int j = 0; j < 4; ++j) {
            float m0 = aw.x - xj[j];
            float m1 = aw.z - xj[j];
            float p0 = __builtin_amdgcn_exp2f(-(m0 * m0));
            float p1 = __builtin_amdgcn_exp2f(-(m1 * m1));
            acc2[j].x = fmaf(p0, aw.y, acc2[j].x);
            acc2[j].y = fmaf(p1, aw.w, acc2[j].y);
        }
        aw = aw_n;
        xs = xs_n;
    }

    // ============ epilogue: sigmoid + float4 stores ============
    {
        float4 o0, o1;
        float* p0 = (float*)&o0;
        float* p1 = (float*)&o1;
        #pragma unroll
        for (int j = 0; j < 4; ++j) {
            float ex0 = __builtin_amdgcn_exp2f(-LOG2E * acc2[j].x);
            float ex1 = __builtin_amdgcn_exp2f(-LOG2E * acc2[j].y);
            p0[j] = __builtin_amdgcn_rcpf(1.0f + ex0);
            p1[j] = __builtin_amdgcn_rcpf(1.0f + ex1);
        }
        size_t b0 = 2 * ty;
        *(float4*)&out[b0 * NE + e0 + 4 * tx] = o0;
        *(float4*)&out[(b0 + 1) * NE + e0 + 4 * tx] = o1;
    }
}

extern "C" void kernel_launch(void* const* d_in, const int* in_sizes, int n_in,
                              void* d_out, int out_size, void* d_ws, size_t ws_size,
                              hipStream_t stream) {
    const int*   e1_idx  = (const int*)d_in[0];
    const int*   r_idx   = (const int*)d_in[1];
    const float* Ew      = (const float*)d_in[2];
    const float* Rw      = (const float*)d_in[3];
    const float* num_lit = (const float*)d_in[4];
    const float* cvec    = (const float*)d_in[5];
    const float* var     = (const float*)d_in[6];
    const float* nfw     = (const float*)d_in[7];
    float* out = (float*)d_out;

    DistMult_prep_kernel<<<8, NTHREADS, 0, stream>>>(
        e1_idx, r_idx, Ew, Rw, num_lit, cvec, var, nfw, (unsigned char*)d_ws);
    DistMult_KBLN_79164837200204_kernel<<<NE / EBLK, NTHREADS, 0, stream>>>(
        Ew, num_lit, var, (const unsigned char*)d_ws, out);
}

// Round 14
// 53.894 us; speedup vs baseline: 1.1620x; 1.1620x over previous
//
#include <hip/hip_runtime.h>

#define NB 64
#define NE 40000
#define DIM 200
#define NL 100
#define EBLK 16
#define NTHREADS 256
#define D4 50          // float4 per E row
#define L4 25          // float4 per num_lit row
#define LOG2E 1.4426950408889634f

#define WS_E1R 0       // bf16 [64][224] (e1*r):             28672 B
#define WS_ASW 28672   // f32 [64][100][2] b-major {as,w}:    51200 B
                       // total ws use: 79872 B  (SESSION RULE: <= 79872)

// LDS arena (phase-disjoint, barriers between):
//   probe  : pA [0,4096) + pB [4096,5120)
//   phase 1: Bm [0,4096)  (16 rows x 128 bf16, swizzled, per K-half)
//   scatter: scat [0,4352)   (64 x 17 f32)
//   phase 2: xsF [0,8000)    (100 x 20 f32, padded row)
#define PA_OFF   0
#define PB_OFF   4096
#define BM_OFF   0
#define SCAT_OFF 0
#define XS_OFF   0
#define SMEM_BYTES 8192

typedef float f32x4 __attribute__((ext_vector_type(4)));
typedef short bf16x8 __attribute__((ext_vector_type(8)));
// SESSION RULE (r4/r5/r7/r8/r9): NO f32x2 packed arithmetic — every build
// using it failed with build-varying absmax 0.027-0.063. Scalar math only.
// (float4 loads with scalar component use are fine.)

__device__ __forceinline__ unsigned int f2bf(float f) {
    unsigned int u = __float_as_uint(f);
    return (u + 0x7fffu + ((u >> 16) & 1u)) >> 16;  // RNE
}
__device__ __forceinline__ unsigned int packbf(float a, float b) {
    return f2bf(a) | (f2bf(b) << 16);
}

// ---------------- pre-kernel: bake e1*r (bf16) and asw (f32) into d_ws ----------------
__global__ void DistMult_prep_kernel(
    const int* __restrict__ e1_idx, const int* __restrict__ r_idx,
    const float* __restrict__ Ew, const float* __restrict__ Rw,
    const float* __restrict__ num_lit, const float* __restrict__ cvec,
    const float* __restrict__ var, const float* __restrict__ nfw,
    unsigned char* __restrict__ ws)
{
    const int t = blockIdx.x * NTHREADS + threadIdx.x;  // grid 8*256 = 2048
    unsigned int* e1r = (unsigned int*)(ws + WS_E1R);   // 112 uint per row
    const float4* E4 = (const float4*)Ew;
    const float4* R4 = (const float4*)Rw;

    // e1r bf16 [64][224]
    for (int f = t; f < NB * 28; f += 8 * NTHREADS) {
        int b = f / 28, c = f % 28;
        uint4 st = {0u, 0u, 0u, 0u};
        if (c < 25) {
            float4 a0 = E4[(size_t)e1_idx[b] * D4 + 2 * c];
            float4 a1 = E4[(size_t)e1_idx[b] * D4 + 2 * c + 1];
            float4 r0 = R4[(size_t)r_idx[b] * D4 + 2 * c];
            float4 r1 = R4[(size_t)r_idx[b] * D4 + 2 * c + 1];
            st.x = packbf(a0.x * r0.x, a0.y * r0.y);
            st.y = packbf(a0.z * r0.z, a0.w * r0.w);
            st.z = packbf(a1.x * r1.x, a1.y * r1.y);
            st.w = packbf(a1.z * r1.z, a1.w * r1.w);
        }
        *(uint4*)(e1r + (size_t)b * 112 + c * 4) = st;
    }

    // asw f32 b-major [64][100][2]: as = (n_h - c)*s, w = nfw gather.
    float2* asw = (float2*)(ws + WS_ASW);
    for (int f = t; f < NL * NB; f += 8 * NTHREADS) {
        int b = f / NL, l = f - b * NL;
        float s = sqrtf(LOG2E / var[l]);
        float2 v;
        v.x = (num_lit[(size_t)e1_idx[b] * NL + l] - cvec[l]) * s;
        v.y = nfw[(size_t)r_idx[b] * NL + l];
        asw[f] = v;   // f == b*100 + l
    }
}

// ---------------- main kernel ----------------
// 2500 blocks x 4 waves = 10000 waves (9.8/SIMD supplied, 8 resident) —
// doubles r12's latency hiding. Per thread: 1 b x 4 e outputs.
// Phase 1: MFMA, A-fragments DIRECT from ws (L2, linear); B staged in LDS.
// Probe+scatter bridge (r6-verified) maps acc -> (b,e) exactly.
__global__ __launch_bounds__(NTHREADS, 8)
void DistMult_KBLN_79164837200204_kernel(
    const float* __restrict__ Ew, const float* __restrict__ num_lit,
    const float* __restrict__ var,
    const unsigned char* __restrict__ ws, float* __restrict__ out)
{
    __shared__ __align__(16) char smem[SMEM_BYTES];
    __shared__ float sS[NL];

    const int t = threadIdx.x;
    // Bijective XCD-chunked swizzle (m204), nwg = 2500.
    const int nq = (NE / EBLK) >> 3, nr = (NE / EBLK) & 7;
    const int xcd = blockIdx.x & 7, sub = blockIdx.x >> 3;
    const int wg = (xcd < nr ? xcd * (nq + 1) : nr * (nq + 1) + (xcd - nr) * nq) + sub;
    const int e0 = wg * EBLK;

    const int L = t & 63, w = t >> 6;
    const int l15 = L & 15, lq = L >> 4;
    const int tx = t & 3, ty = t >> 2;   // thread owns b = ty, e = e0+4tx..+3

    if (t < NL) sS[t] = sqrtf(LOG2E / var[t]);

    // ======== layout probe (r6-verified pattern-probe): acc -> (b,e) ========
    unsigned short* pA = (unsigned short*)(smem + PA_OFF);  // [64][32] bf16
    unsigned short* pB = (unsigned short*)(smem + PB_OFF);  // [16][32] bf16
    for (int i = t; i < 1024; i += NTHREADS) ((unsigned int*)pA)[i] = 0u;
    for (int i = t; i < 256;  i += NTHREADS) ((unsigned int*)pB)[i] = 0u;
    __syncthreads();
    if (t < 64) {
        pA[t * 32]     = (unsigned short)f2bf(256.0f * t);
        pA[t * 32 + 1] = (unsigned short)f2bf(1.0f);
    } else if (t < 80) {
        int e = t - 64;
        pB[e * 32]     = (unsigned short)f2bf(1.0f);
        pB[e * 32 + 1] = (unsigned short)f2bf((float)e);
    }
    __syncthreads();
    int ib0[4];
    {
        bf16x8 afp = *(const bf16x8*)(pA + (16 * w + l15) * 32 + lq * 8);
        bf16x8 b0p = *(const bf16x8*)(pB + l15 * 32 + lq * 8);
        f32x4 z = {0.f, 0.f, 0.f, 0.f};
        f32x4 p0 = __builtin_amdgcn_mfma_f32_16x16x32_bf16(afp, b0p, z, 0, 0, 0);
        #pragma unroll
        for (int r = 0; r < 4; ++r) ib0[r] = (int)p0[r];
    }
    __syncthreads();

    f32x4 acc0 = {0.f, 0.f, 0.f, 0.f};
    const float4* E4 = (const float4*)Ew;

    // ============ phase 1: MFMA; A direct from ws, B via LDS (2 K-halves) ============
    #pragma unroll
    for (int h = 0; h < 2; ++h) {
        const int nc = h ? 12 : 16;  // 16B chunks per B row this half
        for (int f = t; f < EBLK * nc; f += NTHREADS) {
            int e = f / nc, c = f % nc;
            int dg = h * 128 + c * 8;
            uint4 st = {0u, 0u, 0u, 0u};
            if (dg <= DIM - 8) {
                float4 v0 = E4[(size_t)(e0 + e) * D4 + (dg >> 2)];
                float4 v1 = E4[(size_t)(e0 + e) * D4 + (dg >> 2) + 1];
                st.x = packbf(v0.x, v0.y);
                st.y = packbf(v0.z, v0.w);
                st.z = packbf(v1.x, v1.y);
                st.w = packbf(v1.z, v1.w);
            }
            int off = (e * 256 + c * 16) ^ ((e & 7) << 4);
            *(uint4*)(smem + BM_OFF + off) = st;
        }
        __syncthreads();

        const int nst = h ? 3 : 4;
        const int arow = 16 * w + l15;            // e1r row, 448 B stride
        const int bswz = (l15 & 7) << 4;
        #pragma unroll
        for (int s = 0; s < 4; ++s) {
            if (s < nst) {
                int kb = s * 64 + lq * 16;
                bf16x8 af = *(const bf16x8*)(ws + WS_E1R + arow * 448 + h * 256 + kb);
                bf16x8 b0 = *(const bf16x8*)(smem + BM_OFF + ((l15 * 256 + kb) ^ bswz));
                acc0 = __builtin_amdgcn_mfma_f32_16x16x32_bf16(af, b0, acc0, 0, 0, 0);
            }
        }
        __syncthreads();
    }

    // ======== scatter acc via probed coords; gather at (b=ty, e=4tx+j) ========
    float* scat = (float*)(smem + SCAT_OFF);      // [64][17]
    #pragma unroll
    for (int r = 0; r < 4; ++r)
        scat[(ib0[r] >> 8) * 17 + (ib0[r] & 255)] = acc0[r];
    __syncthreads();

    float acc[4];
    #pragma unroll
    for (int j = 0; j < 4; ++j)
        acc[j] = scat[ty * 17 + 4 * tx + j];
    __syncthreads();

    // ======== stage xsF[100][20] (padded rows; 16B-aligned, bank-clean) ========
    const float4* N4 = (const float4*)num_lit;
    float* xsF = (float*)(smem + XS_OFF);
    for (int f = t; f < EBLK * L4; f += NTHREADS) {
        int e = f & 15, l4 = f >> 4;
        float4 v = N4[(size_t)(e0 + e) * L4 + l4];
        const float* vf = (const float*)&v;
        #pragma unroll
        for (int k = 0; k < 4; ++k)
            xsF[(4 * l4 + k) * 20 + e] = vf[k] * sS[4 * l4 + k];
    }
    __syncthreads();

    // ============ phase 2: 50 x (1 global float4 = 2 l's of {as,w}) ============
    const float4* ASWB = (const float4*)(ws + WS_ASW);  // b-major, 50 float4/row
    #pragma unroll 2
    for (int l2 = 0; l2 < NL / 2; ++l2) {
        float4 awp = ASWB[ty * 50 + l2];  // {as_2l2, w_2l2, as_2l2+1, w_2l2+1}
        float4 xa = *(const float4*)(xsF + (2 * l2) * 20 + 4 * tx);
        float4 xb = *(const float4*)(xsF + (2 * l2 + 1) * 20 + 4 * tx);
        float xja[4] = { xa.x, xa.y, xa.z, xa.w };
        float xjb[4] = { xb.x, xb.y, xb.z, xb.w };
        #pragma unroll
        for (int j = 0; j < 4; ++j) {
            float m0 = awp.x - xja[j];
            float p0 = __builtin_amdgcn_exp2f(-(m0 * m0));
            acc[j] = fmaf(p0, awp.y, acc[j]);
        }
        #pragma unroll
        for (int j = 0; j < 4; ++j) {
            float m1 = awp.z - xjb[j];
            float p1 = __builtin_amdgcn_exp2f(-(m1 * m1));
            acc[j] = fmaf(p1, awp.w, acc[j]);
        }
    }

    // ============ epilogue: sigmoid + one float4 store ============
    {
        float4 o;
        float* op = (float*)&o;
        #pragma unroll
        for (int j = 0; j < 4; ++j) {
            float ex = __builtin_amdgcn_exp2f(-LOG2E * acc[j]);
            op[j] = __builtin_amdgcn_rcpf(1.0f + ex);
        }
        *(float4*)&out[(size_t)ty * NE + e0 + 4 * tx] = o;
    }
}

extern "C" void kernel_launch(void* const* d_in, const int* in_sizes, int n_in,
                              void* d_out, int out_size, void* d_ws, size_t ws_size,
                              hipStream_t stream) {
    const int*   e1_idx  = (const int*)d_in[0];
    const int*   r_idx   = (const int*)d_in[1];
    const float* Ew      = (const float*)d_in[2];
    const float* Rw      = (const float*)d_in[3];
    const float* num_lit = (const float*)d_in[4];
    const float* cvec    = (const float*)d_in[5];
    const float* var     = (const float*)d_in[6];
    const float* nfw     = (const float*)d_in[7];
    float* out = (float*)d_out;

    DistMult_prep_kernel<<<8, NTHREADS, 0, stream>>>(
        e1_idx, r_idx, Ew, Rw, num_lit, cvec, var, nfw, (unsigned char*)d_ws);
    DistMult_KBLN_79164837200204_kernel<<<NE / EBLK, NTHREADS, 0, stream>>>(
        Ew, num_lit, var, (const unsigned char*)d_ws, out);
}

// Round 15
// 52.333 us; speedup vs baseline: 1.1966x; 1.0298x over previous
//
#include <hip/hip_runtime.h>

#define NB 64
#define NE 40000
#define DIM 200
#define NL 100
#define EBLK 16
#define NTHREADS 256
#define D4 50          // float4 per E row
#define L4 25          // float4 per num_lit row
#define LOG2E 1.4426950408889634f

#define WS_E1R 0       // bf16 [64][224] (e1*r):             28672 B
#define WS_ASW 28672   // f32 [64][100][2] b-major {as,w}:    51200 B
                       // total ws use: 79872 B  (SESSION RULE: <= 79872)

// LDS arena (phase-disjoint, barriers between):
//   probe  : pA [0,4096) + pB [4096,5120)
//   phase 1: Bm [0,4096)  (16 rows x 128 bf16, swizzled, per K-half)
//   scatter: scat [0,4352)   (64 x 17 f32)
//   phase 2: xsF [0,8000)    (100 x 20 f32, padded row)
#define PA_OFF   0
#define PB_OFF   4096
#define BM_OFF   0
#define SCAT_OFF 0
#define XS_OFF   0
#define SMEM_BYTES 8192

typedef float f32x4 __attribute__((ext_vector_type(4)));
typedef short bf16x8 __attribute__((ext_vector_type(8)));
// SESSION RULE (r4/r5/r7/r8/r9): NO f32x2 packed arithmetic — every build
// using it failed with build-varying absmax 0.027-0.063. Scalar math only.
// (float4 loads with scalar component use are fine.)

__device__ __forceinline__ unsigned int f2bf(float f) {
    unsigned int u = __float_as_uint(f);
    return (u + 0x7fffu + ((u >> 16) & 1u)) >> 16;  // RNE
}
__device__ __forceinline__ unsigned int packbf(float a, float b) {
    return f2bf(a) | (f2bf(b) << 16);
}

// ---------------- pre-kernel: bake e1*r (bf16) and asw (f32) into d_ws ----------------
__global__ void DistMult_prep_kernel(
    const int* __restrict__ e1_idx, const int* __restrict__ r_idx,
    const float* __restrict__ Ew, const float* __restrict__ Rw,
    const float* __restrict__ num_lit, const float* __restrict__ cvec,
    const float* __restrict__ var, const float* __restrict__ nfw,
    unsigned char* __restrict__ ws)
{
    const int t = blockIdx.x * NTHREADS + threadIdx.x;  // grid 8*256 = 2048
    unsigned int* e1r = (unsigned int*)(ws + WS_E1R);   // 112 uint per row
    const float4* E4 = (const float4*)Ew;
    const float4* R4 = (const float4*)Rw;

    // e1r bf16 [64][224]
    for (int f = t; f < NB * 28; f += 8 * NTHREADS) {
        int b = f / 28, c = f % 28;
        uint4 st = {0u, 0u, 0u, 0u};
        if (c < 25) {
            float4 a0 = E4[(size_t)e1_idx[b] * D4 + 2 * c];
            float4 a1 = E4[(size_t)e1_idx[b] * D4 + 2 * c + 1];
            float4 r0 = R4[(size_t)r_idx[b] * D4 + 2 * c];
            float4 r1 = R4[(size_t)r_idx[b] * D4 + 2 * c + 1];
            st.x = packbf(a0.x * r0.x, a0.y * r0.y);
            st.y = packbf(a0.z * r0.z, a0.w * r0.w);
            st.z = packbf(a1.x * r1.x, a1.y * r1.y);
            st.w = packbf(a1.z * r1.z, a1.w * r1.w);
        }
        *(uint4*)(e1r + (size_t)b * 112 + c * 4) = st;
    }

    // asw f32 b-major [64][100][2]: as = (n_h - c)*s, w = nfw gather.
    float2* asw = (float2*)(ws + WS_ASW);
    for (int f = t; f < NL * NB; f += 8 * NTHREADS) {
        int b = f / NL, l = f - b * NL;
        float s = sqrtf(LOG2E / var[l]);
        float2 v;
        v.x = (num_lit[(size_t)e1_idx[b] * NL + l] - cvec[l]) * s;
        v.y = nfw[(size_t)r_idx[b] * NL + l];
        asw[f] = v;   // f == b*100 + l
    }
}

// ---------------- main kernel ----------------
// 2500 blocks x 4 waves; thread owns b = ty, e = e0+4tx..+3.
// Phase 1: MFMA, A direct from ws (L2, linear); B staged in LDS.
// Phase 2: unroll-5 groups — immediate offsets + 5 aw loads in flight
// (compiler-scheduled; manual rotation regressed in r13).
__global__ __launch_bounds__(NTHREADS, 4)
void DistMult_KBLN_79164837200204_kernel(
    const float* __restrict__ Ew, const float* __restrict__ num_lit,
    const float* __restrict__ var,
    const unsigned char* __restrict__ ws, float* __restrict__ out)
{
    __shared__ __align__(16) char smem[SMEM_BYTES];
    __shared__ float sS[NL];

    const int t = threadIdx.x;
    // Bijective XCD-chunked swizzle (m204), nwg = 2500.
    const int nq = (NE / EBLK) >> 3, nr = (NE / EBLK) & 7;
    const int xcd = blockIdx.x & 7, sub = blockIdx.x >> 3;
    const int wg = (xcd < nr ? xcd * (nq + 1) : nr * (nq + 1) + (xcd - nr) * nq) + sub;
    const int e0 = wg * EBLK;

    const int L = t & 63, w = t >> 6;
    const int l15 = L & 15, lq = L >> 4;
    const int tx = t & 3, ty = t >> 2;   // thread owns b = ty, e = e0+4tx..+3

    if (t < NL) sS[t] = sqrtf(LOG2E / var[t]);

    // ======== layout probe (r6-verified pattern-probe): acc -> (b,e) ========
    unsigned short* pA = (unsigned short*)(smem + PA_OFF);  // [64][32] bf16
    unsigned short* pB = (unsigned short*)(smem + PB_OFF);  // [16][32] bf16
    for (int i = t; i < 1024; i += NTHREADS) ((unsigned int*)pA)[i] = 0u;
    for (int i = t; i < 256;  i += NTHREADS) ((unsigned int*)pB)[i] = 0u;
    __syncthreads();
    if (t < 64) {
        pA[t * 32]     = (unsigned short)f2bf(256.0f * t);
        pA[t * 32 + 1] = (unsigned short)f2bf(1.0f);
    } else if (t < 80) {
        int e = t - 64;
        pB[e * 32]     = (unsigned short)f2bf(1.0f);
        pB[e * 32 + 1] = (unsigned short)f2bf((float)e);
    }
    __syncthreads();
    int ib0[4];
    {
        bf16x8 afp = *(const bf16x8*)(pA + (16 * w + l15) * 32 + lq * 8);
        bf16x8 b0p = *(const bf16x8*)(pB + l15 * 32 + lq * 8);
        f32x4 z = {0.f, 0.f, 0.f, 0.f};
        f32x4 p0 = __builtin_amdgcn_mfma_f32_16x16x32_bf16(afp, b0p, z, 0, 0, 0);
        #pragma unroll
        for (int r = 0; r < 4; ++r) ib0[r] = (int)p0[r];
    }
    __syncthreads();

    f32x4 acc0 = {0.f, 0.f, 0.f, 0.f};
    const float4* E4 = (const float4*)Ew;

    // ============ phase 1: MFMA; A direct from ws, B via LDS (2 K-halves) ============
    #pragma unroll
    for (int h = 0; h < 2; ++h) {
        const int nc = h ? 12 : 16;  // 16B chunks per B row this half
        for (int f = t; f < EBLK * nc; f += NTHREADS) {
            int e = f / nc, c = f % nc;
            int dg = h * 128 + c * 8;
            uint4 st = {0u, 0u, 0u, 0u};
            if (dg <= DIM - 8) {
                float4 v0 = E4[(size_t)(e0 + e) * D4 + (dg >> 2)];
                float4 v1 = E4[(size_t)(e0 + e) * D4 + (dg >> 2) + 1];
                st.x = packbf(v0.x, v0.y);
                st.y = packbf(v0.z, v0.w);
                st.z = packbf(v1.x, v1.y);
                st.w = packbf(v1.z, v1.w);
            }
            int off = (e * 256 + c * 16) ^ ((e & 7) << 4);
            *(uint4*)(smem + BM_OFF + off) = st;
        }
        __syncthreads();

        const int nst = h ? 3 : 4;
        const int arow = 16 * w + l15;            // e1r row, 448 B stride
        const int bswz = (l15 & 7) << 4;
        #pragma unroll
        for (int s = 0; s < 4; ++s) {
            if (s < nst) {
                int kb = s * 64 + lq * 16;
                bf16x8 af = *(const bf16x8*)(ws + WS_E1R + arow * 448 + h * 256 + kb);
                bf16x8 b0 = *(const bf16x8*)(smem + BM_OFF + ((l15 * 256 + kb) ^ bswz));
                acc0 = __builtin_amdgcn_mfma_f32_16x16x32_bf16(af, b0, acc0, 0, 0, 0);
            }
        }
        __syncthreads();
    }

    // ======== scatter acc via probed coords; gather at (b=ty, e=4tx+j) ========
    float* scat = (float*)(smem + SCAT_OFF);      // [64][17]
    #pragma unroll
    for (int r = 0; r < 4; ++r)
        scat[(ib0[r] >> 8) * 17 + (ib0[r] & 255)] = acc0[r];
    __syncthreads();

    float acc[4];
    #pragma unroll
    for (int j = 0; j < 4; ++j)
        acc[j] = scat[ty * 17 + 4 * tx + j];
    __syncthreads();

    // ======== stage xsF[100][20] (padded rows; 16B-aligned, bank-clean) ========
    const float4* N4 = (const float4*)num_lit;
    float* xsF = (float*)(smem + XS_OFF);
    for (int f = t; f < EBLK * L4; f += NTHREADS) {
        int e = f & 15, l4 = f >> 4;
        float4 v = N4[(size_t)(e0 + e) * L4 + l4];
        const float* vf = (const float*)&v;
        #pragma unroll
        for (int k = 0; k < 4; ++k)
            xsF[(4 * l4 + k) * 20 + e] = vf[k] * sS[4 * l4 + k];
    }
    __syncthreads();

    // ============ phase 2: unroll-5 groups (10 groups x 5 l2-pairs) ============
    const float4* ASWB = (const float4*)(ws + WS_ASW) + (size_t)ty * 50;
    const float* xsT = xsF + 4 * tx;
    #pragma unroll 1
    for (int g = 0; g < 10; ++g) {
        const int base = g * 5;
        #pragma unroll 5
        for (int u = 0; u < 5; ++u) {
            const int l2 = base + u;
            float4 awp = ASWB[l2];  // {as_2l2, w_2l2, as_2l2+1, w_2l2+1}
            float4 xa = *(const float4*)(xsT + (2 * l2) * 20);
            float4 xb = *(const float4*)(xsT + (2 * l2 + 1) * 20);
            float xja[4] = { xa.x, xa.y, xa.z, xa.w };
            float xjb[4] = { xb.x, xb.y, xb.z, xb.w };
            #pragma unroll
            for (int j = 0; j < 4; ++j) {
                float m0 = awp.x - xja[j];
                float p0 = __builtin_amdgcn_exp2f(-(m0 * m0));
                acc[j] = fmaf(p0, awp.y, acc[j]);
            }
            #pragma unroll
            for (int j = 0; j < 4; ++j) {
                float m1 = awp.z - xjb[j];
                float p1 = __builtin_amdgcn_exp2f(-(m1 * m1));
                acc[j] = fmaf(p1, awp.w, acc[j]);
            }
        }
    }

    // ============ epilogue: sigmoid + one float4 store ============
    {
        float4 o;
        float* op = (float*)&o;
        #pragma unroll
        for (int j = 0; j < 4; ++j) {
            float ex = __builtin_amdgcn_exp2f(-LOG2E * acc[j]);
            op[j] = __builtin_amdgcn_rcpf(1.0f + ex);
        }
        *(float4*)&out[(size_t)ty * NE + e0 + 4 * tx] = o;
    }
}

extern "C" void kernel_launch(void* const* d_in, const int* in_sizes, int n_in,
                              void* d_out, int out_size, void* d_ws, size_t ws_size,
                              hipStream_t stream) {
    const int*   e1_idx  = (const int*)d_in[0];
    const int*   r_idx   = (const int*)d_in[1];
    const float* Ew      = (const float*)d_in[2];
    const float* Rw      = (const float*)d_in[3];
    const float* num_lit = (const float*)d_in[4];
    const float* cvec    = (const float*)d_in[5];
    const float* var     = (const float*)d_in[6];
    const float* nfw     = (const float*)d_in[7];
    float* out = (float*)d_out;

    DistMult_prep_kernel<<<8, NTHREADS, 0, stream>>>(
        e1_idx, r_idx, Ew, Rw, num_lit, cvec, var, nfw, (unsigned char*)d_ws);
    DistMult_KBLN_79164837200204_kernel<<<NE / EBLK, NTHREADS, 0, stream>>>(
        Ew, num_lit, var, (const unsigned char*)d_ws, out);
}

// Round 16
// 51.170 us; speedup vs baseline: 1.2238x; 1.0227x over previous
//
#include <hip/hip_runtime.h>

#define NB 64
#define NE 40000
#define DIM 200
#define NL 100
#define EBLK 16
#define NTHREADS 256
#define D4 50          // float4 per E row
#define L4 25          // float4 per num_lit row
#define LOG2E 1.4426950408889634f

#define WS_E1R 0       // bf16 [64][224] (e1*r):             28672 B
#define WS_ASW 28672   // f32 [64][100][2] b-major {as,w}:    51200 B
                       // total ws use: 79872 B  (SESSION RULE: <= 79872)

// LDS arena (phase-disjoint except xsF, which is EXCLUSIVE):
//   probe  : pA [0,4096) + pB [4096,5120)
//   phase 1: Bm [0,4096)
//   scatter: scat [0,4352)
//   phase 2: xsF [5120,13120)   (100 x 20 f32, padded row; no aliasing ->
//            staged early, overlapped with probe/phase-1)
#define PA_OFF   0
#define PB_OFF   4096
#define BM_OFF   0
#define SCAT_OFF 0
#define XS_OFF   5120
#define SMEM_BYTES 13120

typedef float f32x4 __attribute__((ext_vector_type(4)));
typedef short bf16x8 __attribute__((ext_vector_type(8)));
// SESSION RULE (r4/r5/r7/r8/r9): NO f32x2 packed arithmetic — every build
// using it failed with build-varying absmax 0.027-0.063. Scalar math only.
// (float4 loads with scalar component use are fine.)

__device__ __forceinline__ unsigned int f2bf(float f) {
    unsigned int u = __float_as_uint(f);
    return (u + 0x7fffu + ((u >> 16) & 1u)) >> 16;  // RNE
}
__device__ __forceinline__ unsigned int packbf(float a, float b) {
    return f2bf(a) | (f2bf(b) << 16);
}

// ---------------- pre-kernel: bake e1*r (bf16) and asw (f32) into d_ws ----------------
__global__ void DistMult_prep_kernel(
    const int* __restrict__ e1_idx, const int* __restrict__ r_idx,
    const float* __restrict__ Ew, const float* __restrict__ Rw,
    const float* __restrict__ num_lit, const float* __restrict__ cvec,
    const float* __restrict__ var, const float* __restrict__ nfw,
    unsigned char* __restrict__ ws)
{
    const int t = blockIdx.x * NTHREADS + threadIdx.x;  // grid 8*256 = 2048
    unsigned int* e1r = (unsigned int*)(ws + WS_E1R);   // 112 uint per row
    const float4* E4 = (const float4*)Ew;
    const float4* R4 = (const float4*)Rw;

    // e1r bf16 [64][224]
    for (int f = t; f < NB * 28; f += 8 * NTHREADS) {
        int b = f / 28, c = f % 28;
        uint4 st = {0u, 0u, 0u, 0u};
        if (c < 25) {
            float4 a0 = E4[(size_t)e1_idx[b] * D4 + 2 * c];
            float4 a1 = E4[(size_t)e1_idx[b] * D4 + 2 * c + 1];
            float4 r0 = R4[(size_t)r_idx[b] * D4 + 2 * c];
            float4 r1 = R4[(size_t)r_idx[b] * D4 + 2 * c + 1];
            st.x = packbf(a0.x * r0.x, a0.y * r0.y);
            st.y = packbf(a0.z * r0.z, a0.w * r0.w);
            st.z = packbf(a1.x * r1.x, a1.y * r1.y);
            st.w = packbf(a1.z * r1.z, a1.w * r1.w);
        }
        *(uint4*)(e1r + (size_t)b * 112 + c * 4) = st;
    }

    // asw f32 b-major [64][100][2]: as = (n_h - c)*s, w = nfw gather.
    float2* asw = (float2*)(ws + WS_ASW);
    for (int f = t; f < NL * NB; f += 8 * NTHREADS) {
        int b = f / NL, l = f - b * NL;
        float s = sqrtf(LOG2E / var[l]);
        float2 v;
        v.x = (num_lit[(size_t)e1_idx[b] * NL + l] - cvec[l]) * s;
        v.y = nfw[(size_t)r_idx[b] * NL + l];
        asw[f] = v;   // f == b*100 + l
    }
}

// ---------------- main kernel ----------------
// 2500 blocks x 4 waves; thread owns b = ty, e = e0+4tx..+3.
// Phase 1: MFMA, A direct from ws (L2, linear); B staged in LDS.
// Phase 2: FULLY unrolled 50 l2-pairs (immediate offsets, compiler-scheduled
// load hoisting). xsF staged T14-style: global loads issued at kernel top,
// LDS writes after probe (exclusive region), hidden under probe/phase-1.
__global__ __launch_bounds__(NTHREADS, 4)
void DistMult_KBLN_79164837200204_kernel(
    const float* __restrict__ Ew, const float* __restrict__ num_lit,
    const float* __restrict__ var,
    const unsigned char* __restrict__ ws, float* __restrict__ out)
{
    __shared__ __align__(16) char smem[SMEM_BYTES];
    __shared__ float sS[NL];

    const int t = threadIdx.x;
    // Bijective XCD-chunked swizzle (m204), nwg = 2500.
    const int nq = (NE / EBLK) >> 3, nr = (NE / EBLK) & 7;
    const int xcd = blockIdx.x & 7, sub = blockIdx.x >> 3;
    const int wg = (xcd < nr ? xcd * (nq + 1) : nr * (nq + 1) + (xcd - nr) * nq) + sub;
    const int e0 = wg * EBLK;

    const int L = t & 63, w = t >> 6;
    const int l15 = L & 15, lq = L >> 4;
    const int tx = t & 3, ty = t >> 2;   // thread owns b = ty, e = e0+4tx..+3

    if (t < NL) sS[t] = sqrtf(LOG2E / var[t]);

    // ---- T14: issue xs global loads NOW (consumed after probe) ----
    const float4* N4 = (const float4*)num_lit;
    const int f0 = t, f1 = t + NTHREADS;            // f < 400 = 16 rows x 25 f4
    float4 x0, x1;
    { int e = f0 & 15, l4 = f0 >> 4; x0 = N4[(size_t)(e0 + e) * L4 + l4]; }
    if (f1 < EBLK * L4) { int e = f1 & 15, l4 = f1 >> 4; x1 = N4[(size_t)(e0 + e) * L4 + l4]; }

    // ======== layout probe (r6-verified pattern-probe): acc -> (b,e) ========
    unsigned short* pA = (unsigned short*)(smem + PA_OFF);  // [64][32] bf16
    unsigned short* pB = (unsigned short*)(smem + PB_OFF);  // [16][32] bf16
    for (int i = t; i < 1024; i += NTHREADS) ((unsigned int*)pA)[i] = 0u;
    for (int i = t; i < 256;  i += NTHREADS) ((unsigned int*)pB)[i] = 0u;
    __syncthreads();
    if (t < 64) {
        pA[t * 32]     = (unsigned short)f2bf(256.0f * t);
        pA[t * 32 + 1] = (unsigned short)f2bf(1.0f);
    } else if (t < 80) {
        int e = t - 64;
        pB[e * 32]     = (unsigned short)f2bf(1.0f);
        pB[e * 32 + 1] = (unsigned short)f2bf((float)e);
    }
    __syncthreads();
    int ib0[4];
    {
        bf16x8 afp = *(const bf16x8*)(pA + (16 * w + l15) * 32 + lq * 8);
        bf16x8 b0p = *(const bf16x8*)(pB + l15 * 32 + lq * 8);
        f32x4 z = {0.f, 0.f, 0.f, 0.f};
        f32x4 p0 = __builtin_amdgcn_mfma_f32_16x16x32_bf16(afp, b0p, z, 0, 0, 0);
        #pragma unroll
        for (int r = 0; r < 4; ++r) ib0[r] = (int)p0[r];
    }
    __syncthreads();

    // ---- T14: write xsF (exclusive region; visibility via later barriers) ----
    float* xsF = (float*)(smem + XS_OFF);
    {
        int e = f0 & 15, l4 = f0 >> 4;
        const float* vf = (const float*)&x0;
        #pragma unroll
        for (int k = 0; k < 4; ++k)
            xsF[(4 * l4 + k) * 20 + e] = vf[k] * sS[4 * l4 + k];
        if (f1 < EBLK * L4) {
            int e1 = f1 & 15, l41 = f1 >> 4;
            const float* vg = (const float*)&x1;
            #pragma unroll
            for (int k = 0; k < 4; ++k)
                xsF[(4 * l41 + k) * 20 + e1] = vg[k] * sS[4 * l41 + k];
        }
    }

    f32x4 acc0 = {0.f, 0.f, 0.f, 0.f};
    const float4* E4 = (const float4*)Ew;

    // ============ phase 1: MFMA; A direct from ws, B via LDS (2 K-halves) ============
    #pragma unroll
    for (int h = 0; h < 2; ++h) {
        const int nc = h ? 12 : 16;  // 16B chunks per B row this half
        for (int f = t; f < EBLK * nc; f += NTHREADS) {
            int e = f / nc, c = f % nc;
            int dg = h * 128 + c * 8;
            uint4 st = {0u, 0u, 0u, 0u};
            if (dg <= DIM - 8) {
                float4 v0 = E4[(size_t)(e0 + e) * D4 + (dg >> 2)];
                float4 v1 = E4[(size_t)(e0 + e) * D4 + (dg >> 2) + 1];
                st.x = packbf(v0.x, v0.y);
                st.y = packbf(v0.z, v0.w);
                st.z = packbf(v1.x, v1.y);
                st.w = packbf(v1.z, v1.w);
            }
            int off = (e * 256 + c * 16) ^ ((e & 7) << 4);
            *(uint4*)(smem + BM_OFF + off) = st;
        }
        __syncthreads();

        const int nst = h ? 3 : 4;
        const int arow = 16 * w + l15;            // e1r row, 448 B stride
        const int bswz = (l15 & 7) << 4;
        #pragma unroll
        for (int s = 0; s < 4; ++s) {
            if (s < nst) {
                int kb = s * 64 + lq * 16;
                bf16x8 af = *(const bf16x8*)(ws + WS_E1R + arow * 448 + h * 256 + kb);
                bf16x8 b0 = *(const bf16x8*)(smem + BM_OFF + ((l15 * 256 + kb) ^ bswz));
                acc0 = __builtin_amdgcn_mfma_f32_16x16x32_bf16(af, b0, acc0, 0, 0, 0);
            }
        }
        __syncthreads();
    }

    // ======== scatter acc via probed coords; gather at (b=ty, e=4tx+j) ========
    float* scat = (float*)(smem + SCAT_OFF);      // [64][17]
    #pragma unroll
    for (int r = 0; r < 4; ++r)
        scat[(ib0[r] >> 8) * 17 + (ib0[r] & 255)] = acc0[r];
    __syncthreads();   // also makes xsF writes visible block-wide

    float acc[4];
    #pragma unroll
    for (int j = 0; j < 4; ++j)
        acc[j] = scat[ty * 17 + 4 * tx + j];
    // no barrier needed: nothing overwrites scat or xsF below

    // ============ phase 2: FULLY unrolled 50 l2-pairs ============
    const float4* ASWB = (const float4*)(ws + WS_ASW) + (size_t)ty * 50;
    const float* xsT = xsF + 4 * tx;
    #pragma unroll
    for (int l2 = 0; l2 < NL / 2; ++l2) {
        float4 awp = ASWB[l2];  // {as_2l2, w_2l2, as_2l2+1, w_2l2+1}
        float4 xa = *(const float4*)(xsT + (2 * l2) * 20);
        float4 xb = *(const float4*)(xsT + (2 * l2 + 1) * 20);
        float xja[4] = { xa.x, xa.y, xa.z, xa.w };
        float xjb[4] = { xb.x, xb.y, xb.z, xb.w };
        #pragma unroll
        for (int j = 0; j < 4; ++j) {
            float m0 = awp.x - xja[j];
            float p0 = __builtin_amdgcn_exp2f(-(m0 * m0));
            acc[j] = fmaf(p0, awp.y, acc[j]);
        }
        #pragma unroll
        for (int j = 0; j < 4; ++j) {
            float m1 = awp.z - xjb[j];
            float p1 = __builtin_amdgcn_exp2f(-(m1 * m1));
            acc[j] = fmaf(p1, awp.w, acc[j]);
        }
    }

    // ============ epilogue: sigmoid + one float4 store ============
    {
        float4 o;
        float* op = (float*)&o;
        #pragma unroll
        for (int j = 0; j < 4; ++j) {
            float ex = __builtin_amdgcn_exp2f(-LOG2E * acc[j]);
            op[j] = __builtin_amdgcn_rcpf(1.0f + ex);
        }
        *(float4*)&out[(size_t)ty * NE + e0 + 4 * tx] = o;
    }
}

extern "C" void kernel_launch(void* const* d_in, const int* in_sizes, int n_in,
                              void* d_out, int out_size, void* d_ws, size_t ws_size,
                              hipStream_t stream) {
    const int*   e1_idx  = (const int*)d_in[0];
    const int*   r_idx   = (const int*)d_in[1];
    const float* Ew      = (const float*)d_in[2];
    const float* Rw      = (const float*)d_in[3];
    const float* num_lit = (const float*)d_in[4];
    const float* cvec    = (const float*)d_in[5];
    const float* var     = (const float*)d_in[6];
    const float* nfw     = (const float*)d_in[7];
    float* out = (float*)d_out;

    DistMult_prep_kernel<<<8, NTHREADS, 0, stream>>>(
        e1_idx, r_idx, Ew, Rw, num_lit, cvec, var, nfw, (unsigned char*)d_ws);
    DistMult_KBLN_79164837200204_kernel<<<NE / EBLK, NTHREADS, 0, stream>>>(
        Ew, num_lit, var, (const unsigned char*)d_ws, out);
}